// Round 5
// baseline (475.909 us; speedup 1.0000x reference)
//
#include <hip/hip_runtime.h>
#include <stdint.h>

#define N_ROWS 8192
#define F_DIM 256
#define SPLITK 8
#define KSTRIP (N_ROWS / SPLITK)
#define BK 64

typedef __attribute__((ext_vector_type(8))) short s16x8;
typedef __attribute__((ext_vector_type(4))) short s16x4;
typedef __attribute__((ext_vector_type(4))) float f32x4;
typedef __attribute__((address_space(3))) uint32_t lds_u32_t;
typedef __attribute__((address_space(1))) const uint32_t gbl_u32_t;

// async global->LDS, 16B per lane; LDS dest = wave-uniform base + lane*16
__device__ __forceinline__ void gl_lds16(const void* g, void* l) {
    __builtin_amdgcn_global_load_lds((gbl_u32_t*)g, (lds_u32_t*)l, 16, 0, 0);
}

__device__ __forceinline__ unsigned short f2bf(float f) {
    unsigned int u = __float_as_uint(f);
    u += 0x7FFFu + ((u >> 16) & 1u);   // RNE
    return (unsigned short)(u >> 16);
}
__device__ __forceinline__ float bf2f(unsigned short h) {
    return __uint_as_float(((unsigned int)h) << 16);
}
__device__ __forceinline__ s16x8 cvt8(f32x4 a, f32x4 b) {
    s16x8 r;
    r[0] = (short)f2bf(a[0]); r[1] = (short)f2bf(a[1]);
    r[2] = (short)f2bf(a[2]); r[3] = (short)f2bf(a[3]);
    r[4] = (short)f2bf(b[0]); r[5] = (short)f2bf(b[1]);
    r[6] = (short)f2bf(b[2]); r[7] = (short)f2bf(b[3]);
    return r;
}

// ---------------- K1: row sums of (adj + I) -> d = rsqrt; also emit adj as bf16 ----------------
__global__ void k_rowsum(const float* __restrict__ adj, float* __restrict__ dvec,
                         unsigned short* __restrict__ adj_bf) {
    const int row = blockIdx.x;
    const float4* p = (const float4*)(adj + (size_t)row * N_ROWS);
    s16x4* q = (s16x4*)(adj_bf + (size_t)row * N_ROWS);
    float s = 0.f;
#pragma unroll
    for (int i = 0; i < 8; ++i) {
        float4 v = p[threadIdx.x + i * 256];
        s += (v.x + v.y) + (v.z + v.w);
        s16x4 pk;
        pk[0] = (short)f2bf(v.x); pk[1] = (short)f2bf(v.y);
        pk[2] = (short)f2bf(v.z); pk[3] = (short)f2bf(v.w);
        q[threadIdx.x + i * 256] = pk;
    }
#pragma unroll
    for (int off = 32; off > 0; off >>= 1) s += __shfl_down(s, off, 64);
    __shared__ float red[4];
    if ((threadIdx.x & 63) == 0) red[threadIdx.x >> 6] = s;
    __syncthreads();
    if (threadIdx.x == 0) {
        float t = red[0] + red[1] + red[2] + red[3] + 1.0f;  // +I
        dvec[row] = rsqrtf(t);
    }
}

// ---------------- K1c: weight [t][j] fp32 -> wt_t [j][t] bf16 ----------------
__global__ void k_wt(const float* __restrict__ w, unsigned short* __restrict__ wt) {
    const int j = blockIdx.x, t = threadIdx.x;
    wt[j * F_DIM + t] = f2bf(w[t * F_DIM + j]);
}

// ---------------- K2: sup'[r][j] = d_r * (X @ W)[r][j]  -> sup (row-major) AND sup_t (transposed)
// tile 64x128, 4 waves (each 32x64 = 2x4 frags of 16x16x32), grid (128, 2) = 256 blocks
__global__ __launch_bounds__(256, 2)
void k_support(const float* __restrict__ input, const unsigned short* __restrict__ wt,
               const float* __restrict__ dvec, unsigned short* __restrict__ sup,
               unsigned short* __restrict__ sup_t) {
    __shared__ float As[64 * 32];           // 8 KB fp32 A tile, swizzled
    __shared__ unsigned short Bs[128 * 32]; // 8 KB bf16 B tile, swizzled
    const int tid = threadIdx.x, lane = tid & 63, wid = tid >> 6;
    const int wm = wid & 1, wn = wid >> 1;
    const int l15 = lane & 15, q4 = lane >> 4;
    const int m0 = blockIdx.x * 64, n0 = blockIdx.y * 128;

    uint32_t aoff[2], alds[2], boff[2], blds[2];
#pragma unroll
    for (int r = 0; r < 2; ++r) {
        int idx = r * 256 + tid;
        int row = idx >> 3;                    // 0..63
        int cg = (idx & 7) ^ (row & 7);
        aoff[r] = (uint32_t)(m0 + row) * F_DIM + cg * 4;
        alds[r] = (uint32_t)(r * 1024 + wid * 256);   // float offset, wave-uniform
    }
#pragma unroll
    for (int r = 0; r < 2; ++r) {
        int idx = r * 256 + tid;
        int row = idx >> 2;                    // 0..127
        int cg = (idx & 3) ^ ((row >> 1) & 3);
        boff[r] = (uint32_t)(n0 + row) * F_DIM + cg * 8;
        blds[r] = (uint32_t)(r * 2048 + wid * 512);   // ushort offset, wave-uniform
    }

    const int ra7 = l15 & 7;
    const int rb3 = (l15 >> 1) & 3;
    const f32x4* aptr[2][2];
    const s16x8* bptr[4];
#pragma unroll
    for (int a = 0; a < 2; ++a)
#pragma unroll
        for (int j = 0; j < 2; ++j)
            aptr[a][j] = (const f32x4*)(As + (wm * 32 + a * 16 + l15) * 32
                                        + (((2 * q4 + j) ^ ra7) * 4));
#pragma unroll
    for (int b = 0; b < 4; ++b)
        bptr[b] = (const s16x8*)(Bs + (wn * 64 + b * 16 + l15) * 32 + ((q4 ^ rb3) * 8));

    f32x4 acc[2][4];
#pragma unroll
    for (int a = 0; a < 2; ++a)
#pragma unroll
        for (int b = 0; b < 4; ++b) acc[a][b] = (f32x4){0.f, 0.f, 0.f, 0.f};

#pragma unroll 1
    for (int it = 0; it < F_DIM / 32; ++it) {
        __syncthreads();
#pragma unroll
        for (int r = 0; r < 2; ++r) gl_lds16(input + aoff[r], As + alds[r]);
#pragma unroll
        for (int r = 0; r < 2; ++r) gl_lds16(wt + boff[r], Bs + blds[r]);
        __syncthreads();
        s16x8 af[2];
#pragma unroll
        for (int a = 0; a < 2; ++a) af[a] = cvt8(aptr[a][0][0], aptr[a][1][0]);
#pragma unroll
        for (int b = 0; b < 4; ++b) {
            s16x8 bf = *bptr[b];
#pragma unroll
            for (int a = 0; a < 2; ++a)
                acc[a][b] = __builtin_amdgcn_mfma_f32_16x16x32_bf16(af[a], bf, acc[a][b], 0, 0, 0);
        }
#pragma unroll
        for (int r = 0; r < 2; ++r) aoff[r] += 32;
#pragma unroll
        for (int r = 0; r < 2; ++r) boff[r] += 32;
    }

#pragma unroll
    for (int a = 0; a < 2; ++a) {
        const int rbase = m0 + wm * 32 + a * 16 + q4 * 4;
        float dv[4];
#pragma unroll
        for (int r = 0; r < 4; ++r) dv[r] = dvec[rbase + r];
#pragma unroll
        for (int b = 0; b < 4; ++b) {
            const int col = n0 + wn * 64 + b * 16 + l15;
            f32x4 c = acc[a][b];
            s16x4 pk;
#pragma unroll
            for (int r = 0; r < 4; ++r) {
                unsigned short h = f2bf(dv[r] * c[r]);
                pk[r] = (short)h;
                sup[(size_t)(rbase + r) * F_DIM + col] = h;
            }
            *(s16x4*)(sup_t + (size_t)col * N_ROWS + rbase) = pk;  // transposed copy
        }
    }
}

// ---------------- K3: part[s][i][j] = sum_{k in strip s} adj_bf[i][k]*sup'[k][j] ----------------
// all-bf16; tile 64x256, BK=64, 4 waves, grid (128, SPLITK=8) = 1024 blocks, 3 blocks/CU target
__global__ __launch_bounds__(256, 3)
void k_main(const unsigned short* __restrict__ adj_bf, const unsigned short* __restrict__ sup_t,
            float* __restrict__ part) {
    __shared__ unsigned short As[64 * 64];  // 8 KB bf16 A tile, swizzled
    __shared__ unsigned short Bs[256 * 64]; // 32 KB bf16 B tile, swizzled
    const int tid = threadIdx.x, lane = tid & 63, wid = tid >> 6;
    const int l15 = lane & 15, q4 = lane >> 4;
    const int m0 = blockIdx.x * 64;
    const int kbase = blockIdx.y * KSTRIP;

    // A staging: 2 rounds x (256 thr x 16B) = 8 KB; rows of 64 bf16 = 8 chunks of 16B
    uint32_t aoff[2], alds[2];
#pragma unroll
    for (int r = 0; r < 2; ++r) {
        int idx = r * 256 + tid;
        int row = idx >> 3;
        int cg = (idx & 7) ^ (row & 7);
        aoff[r] = (uint32_t)(m0 + row) * N_ROWS + kbase + cg * 8;
        alds[r] = (uint32_t)(r * 2048 + wid * 512);  // ushort offset, wave-uniform
    }
    // B staging: 8 rounds x 4 KB = 32 KB
    uint32_t boff[8], blds[8];
#pragma unroll
    for (int r = 0; r < 8; ++r) {
        int idx = r * 256 + tid;
        int row = idx >> 3;
        int cg = (idx & 7) ^ (row & 7);
        boff[r] = (uint32_t)row * N_ROWS + kbase + cg * 8;
        blds[r] = (uint32_t)(r * 2048 + wid * 512);
    }

    const int ra7 = l15 & 7;
    const s16x8* aptr[4][2];
    const s16x8* bptr[4][2];
#pragma unroll
    for (int a = 0; a < 4; ++a)
#pragma unroll
        for (int h = 0; h < 2; ++h)
            aptr[a][h] = (const s16x8*)(As + (a * 16 + l15) * 64 + (((h * 4 + q4) ^ ra7) * 8));
#pragma unroll
    for (int b = 0; b < 4; ++b)
#pragma unroll
        for (int h = 0; h < 2; ++h)
            bptr[b][h] = (const s16x8*)(Bs + (wid * 64 + b * 16 + l15) * 64
                                        + (((h * 4 + q4) ^ ra7) * 8));

    f32x4 acc[4][4];
#pragma unroll
    for (int a = 0; a < 4; ++a)
#pragma unroll
        for (int b = 0; b < 4; ++b) acc[a][b] = (f32x4){0.f, 0.f, 0.f, 0.f};

#pragma unroll 1
    for (int it = 0; it < KSTRIP / BK; ++it) {
        __syncthreads();
#pragma unroll
        for (int r = 0; r < 2; ++r) gl_lds16(adj_bf + aoff[r], As + alds[r]);
#pragma unroll
        for (int r = 0; r < 8; ++r) gl_lds16(sup_t + boff[r], Bs + blds[r]);
        __syncthreads();
#pragma unroll
        for (int h = 0; h < 2; ++h) {
            s16x8 af[4];
#pragma unroll
            for (int a = 0; a < 4; ++a) af[a] = *aptr[a][h];
#pragma unroll
            for (int b = 0; b < 4; ++b) {
                s16x8 bf = *bptr[b][h];
#pragma unroll
                for (int a = 0; a < 4; ++a)
                    acc[a][b] = __builtin_amdgcn_mfma_f32_16x16x32_bf16(af[a], bf, acc[a][b], 0, 0, 0);
            }
        }
#pragma unroll
        for (int r = 0; r < 2; ++r) aoff[r] += BK;
#pragma unroll
        for (int r = 0; r < 8; ++r) boff[r] += BK;
    }

    float* p = part + (size_t)blockIdx.y * ((size_t)N_ROWS * F_DIM);
#pragma unroll
    for (int a = 0; a < 4; ++a) {
        const int rbase = m0 + a * 16 + q4 * 4;
#pragma unroll
        for (int b = 0; b < 4; ++b) {
            const int col = wid * 64 + b * 16 + l15;
            f32x4 c = acc[a][b];
#pragma unroll
            for (int r = 0; r < 4; ++r)
                p[(size_t)(rbase + r) * F_DIM + col] = c[r];
        }
    }
}

// ---------------- K4: out = d_i * (sum_s part_s + sup') + bias ----------------
__global__ void k_reduce(const float* __restrict__ part, const unsigned short* __restrict__ sup,
                         const float* __restrict__ dvec, const float* __restrict__ bias,
                         float* __restrict__ out) {
    const int gid = blockIdx.x * 256 + threadIdx.x;
    const int row = gid >> 6;
    const int c = (gid & 63) * 4;
    const size_t off = (size_t)row * F_DIM + c;
    const size_t PS = (size_t)N_ROWS * F_DIM;
    f32x4 v = *(const f32x4*)(part + off);
#pragma unroll
    for (int s = 1; s < SPLITK; ++s) v += *(const f32x4*)(part + s * PS + off);
    const float d = dvec[row];
    const unsigned short* sp = sup + off;
    const f32x4 bb = *(const f32x4*)(bias + c);
    f32x4 o;
#pragma unroll
    for (int r = 0; r < 4; ++r) o[r] = d * (v[r] + bf2f(sp[r])) + bb[r];
    *(f32x4*)(out + off) = o;
}

extern "C" void kernel_launch(void* const* d_in, const int* in_sizes, int n_in,
                              void* d_out, int out_size, void* d_ws, size_t ws_size,
                              hipStream_t stream) {
    const float* input  = (const float*)d_in[0];
    const float* adj    = (const float*)d_in[1];
    const float* weight = (const float*)d_in[2];
    const float* bias   = (const float*)d_in[3];
    float* out = (float*)d_out;

    char* ws = (char*)d_ws;
    unsigned short* adj_bf = (unsigned short*)ws;                                   // 128 MB
    char* ws2 = ws + (size_t)N_ROWS * N_ROWS * 2;
    float* dvec           = (float*)ws2;                                            // 32 KB
    unsigned short* wt    = (unsigned short*)(ws2 + (32 << 10));                    // 128 KB
    unsigned short* sup   = (unsigned short*)(ws2 + (32 << 10) + (128 << 10));      // 4 MB
    unsigned short* sup_t = (unsigned short*)(ws2 + (32 << 10) + (128 << 10)
                                              + (size_t)N_ROWS * F_DIM * 2);        // 4 MB
    float* part           = (float*)(ws2 + (32 << 10) + (128 << 10)
                                     + 2 * (size_t)N_ROWS * F_DIM * 2);             // 64 MB

    k_wt<<<dim3(F_DIM), dim3(F_DIM), 0, stream>>>(weight, wt);
    k_rowsum<<<dim3(N_ROWS), dim3(256), 0, stream>>>(adj, dvec, adj_bf);
    k_support<<<dim3(128, 2), dim3(256), 0, stream>>>(input, wt, dvec, sup, sup_t);
    k_main<<<dim3(128, SPLITK), dim3(256), 0, stream>>>(adj_bf, sup_t, part);
    k_reduce<<<dim3((N_ROWS * F_DIM / 4) / 256), dim3(256), 0, stream>>>(part, sup, dvec, bias, out);
}

// Round 6
// 466.494 us; speedup vs baseline: 1.0202x; 1.0202x over previous
//
#include <hip/hip_runtime.h>
#include <stdint.h>

#define N_ROWS 8192
#define F_DIM 256
#define SPLITK 4
#define KSTRIP (N_ROWS / SPLITK)
#define BK 64

typedef __attribute__((ext_vector_type(8))) short s16x8;
typedef __attribute__((ext_vector_type(4))) short s16x4;
typedef __attribute__((ext_vector_type(4))) float f32x4;
typedef __attribute__((address_space(3))) uint32_t lds_u32_t;
typedef __attribute__((address_space(1))) const uint32_t gbl_u32_t;

// async global->LDS, 16B per lane; LDS dest = wave-uniform base + lane*16
__device__ __forceinline__ void gl_lds16(const void* g, void* l) {
    __builtin_amdgcn_global_load_lds((gbl_u32_t*)g, (lds_u32_t*)l, 16, 0, 0);
}

__device__ __forceinline__ unsigned short f2bf(float f) {
    unsigned int u = __float_as_uint(f);
    u += 0x7FFFu + ((u >> 16) & 1u);   // RNE
    return (unsigned short)(u >> 16);
}
__device__ __forceinline__ float bf2f(unsigned short h) {
    return __uint_as_float(((unsigned int)h) << 16);
}
__device__ __forceinline__ s16x8 cvt8(f32x4 a, f32x4 b) {
    s16x8 r;
    r[0] = (short)f2bf(a[0]); r[1] = (short)f2bf(a[1]);
    r[2] = (short)f2bf(a[2]); r[3] = (short)f2bf(a[3]);
    r[4] = (short)f2bf(b[0]); r[5] = (short)f2bf(b[1]);
    r[6] = (short)f2bf(b[2]); r[7] = (short)f2bf(b[3]);
    return r;
}

// ---------------- K1: row sums of (adj + I) -> d = rsqrt; also emit adj as bf16 ----------------
__global__ void k_rowsum(const float* __restrict__ adj, float* __restrict__ dvec,
                         unsigned short* __restrict__ adj_bf) {
    const int row = blockIdx.x;
    const float4* p = (const float4*)(adj + (size_t)row * N_ROWS);
    s16x4* q = (s16x4*)(adj_bf + (size_t)row * N_ROWS);
    float s = 0.f;
#pragma unroll
    for (int i = 0; i < 8; ++i) {
        float4 v = p[threadIdx.x + i * 256];
        s += (v.x + v.y) + (v.z + v.w);
        s16x4 pk;
        pk[0] = (short)f2bf(v.x); pk[1] = (short)f2bf(v.y);
        pk[2] = (short)f2bf(v.z); pk[3] = (short)f2bf(v.w);
        q[threadIdx.x + i * 256] = pk;
    }
#pragma unroll
    for (int off = 32; off > 0; off >>= 1) s += __shfl_down(s, off, 64);
    __shared__ float red[4];
    if ((threadIdx.x & 63) == 0) red[threadIdx.x >> 6] = s;
    __syncthreads();
    if (threadIdx.x == 0) {
        float t = red[0] + red[1] + red[2] + red[3] + 1.0f;  // +I
        dvec[row] = rsqrtf(t);
    }
}

// ---------------- K1c: weight [t][j] fp32 -> wt_t [j][t] bf16 ----------------
__global__ void k_wt(const float* __restrict__ w, unsigned short* __restrict__ wt) {
    const int j = blockIdx.x, t = threadIdx.x;
    wt[j * F_DIM + t] = f2bf(w[t * F_DIM + j]);
}

// ---------------- K2: sup'[r][j] = d_r * (X @ W)[r][j]  -> sup (row-major) AND sup_t (transposed)
// tile 64x128, 4 waves (each 32x64 = 2x4 frags of 16x16x32), grid (128, 2) = 256 blocks
__global__ __launch_bounds__(256, 2)
void k_support(const float* __restrict__ input, const unsigned short* __restrict__ wt,
               const float* __restrict__ dvec, unsigned short* __restrict__ sup,
               unsigned short* __restrict__ sup_t) {
    __shared__ float As[64 * 32];           // 8 KB fp32 A tile, swizzled
    __shared__ unsigned short Bs[128 * 32]; // 8 KB bf16 B tile, swizzled
    const int tid = threadIdx.x, lane = tid & 63, wid = tid >> 6;
    const int wm = wid & 1, wn = wid >> 1;
    const int l15 = lane & 15, q4 = lane >> 4;
    const int m0 = blockIdx.x * 64, n0 = blockIdx.y * 128;

    uint32_t aoff[2], alds[2], boff[2], blds[2];
#pragma unroll
    for (int r = 0; r < 2; ++r) {
        int idx = r * 256 + tid;
        int row = idx >> 3;                    // 0..63
        int cg = (idx & 7) ^ (row & 7);
        aoff[r] = (uint32_t)(m0 + row) * F_DIM + cg * 4;
        alds[r] = (uint32_t)(r * 1024 + wid * 256);   // float offset, wave-uniform
    }
#pragma unroll
    for (int r = 0; r < 2; ++r) {
        int idx = r * 256 + tid;
        int row = idx >> 2;                    // 0..127
        int cg = (idx & 3) ^ ((row >> 1) & 3);
        boff[r] = (uint32_t)(n0 + row) * F_DIM + cg * 8;
        blds[r] = (uint32_t)(r * 2048 + wid * 512);   // ushort offset, wave-uniform
    }

    const int ra7 = l15 & 7;
    const int rb3 = (l15 >> 1) & 3;
    const f32x4* aptr[2][2];
    const s16x8* bptr[4];
#pragma unroll
    for (int a = 0; a < 2; ++a)
#pragma unroll
        for (int j = 0; j < 2; ++j)
            aptr[a][j] = (const f32x4*)(As + (wm * 32 + a * 16 + l15) * 32
                                        + (((2 * q4 + j) ^ ra7) * 4));
#pragma unroll
    for (int b = 0; b < 4; ++b)
        bptr[b] = (const s16x8*)(Bs + (wn * 64 + b * 16 + l15) * 32 + ((q4 ^ rb3) * 8));

    f32x4 acc[2][4];
#pragma unroll
    for (int a = 0; a < 2; ++a)
#pragma unroll
        for (int b = 0; b < 4; ++b) acc[a][b] = (f32x4){0.f, 0.f, 0.f, 0.f};

#pragma unroll 1
    for (int it = 0; it < F_DIM / 32; ++it) {
        __syncthreads();
#pragma unroll
        for (int r = 0; r < 2; ++r) gl_lds16(input + aoff[r], As + alds[r]);
#pragma unroll
        for (int r = 0; r < 2; ++r) gl_lds16(wt + boff[r], Bs + blds[r]);
        __syncthreads();
        s16x8 af[2];
#pragma unroll
        for (int a = 0; a < 2; ++a) af[a] = cvt8(aptr[a][0][0], aptr[a][1][0]);
#pragma unroll
        for (int b = 0; b < 4; ++b) {
            s16x8 bf = *bptr[b];
#pragma unroll
            for (int a = 0; a < 2; ++a)
                acc[a][b] = __builtin_amdgcn_mfma_f32_16x16x32_bf16(af[a], bf, acc[a][b], 0, 0, 0);
        }
#pragma unroll
        for (int r = 0; r < 2; ++r) aoff[r] += 32;
#pragma unroll
        for (int r = 0; r < 2; ++r) boff[r] += 32;
    }

#pragma unroll
    for (int a = 0; a < 2; ++a) {
        const int rbase = m0 + wm * 32 + a * 16 + q4 * 4;
        float dv[4];
#pragma unroll
        for (int r = 0; r < 4; ++r) dv[r] = dvec[rbase + r];
#pragma unroll
        for (int b = 0; b < 4; ++b) {
            const int col = n0 + wn * 64 + b * 16 + l15;
            f32x4 c = acc[a][b];
            s16x4 pk;
#pragma unroll
            for (int r = 0; r < 4; ++r) {
                unsigned short h = f2bf(dv[r] * c[r]);
                pk[r] = (short)h;
                sup[(size_t)(rbase + r) * F_DIM + col] = h;
            }
            *(s16x4*)(sup_t + (size_t)col * N_ROWS + rbase) = pk;  // transposed copy
        }
    }
}

// ---------------- K3: part[s][i][j] = sum_{k in strip s} adj_bf[i][k]*sup'[k][j] ----------------
// all-bf16; tile 64x256, BK=64, 4 waves, grid (128, SPLITK=4) = 512 blocks, 2 blocks/CU
__global__ __launch_bounds__(256, 2)
void k_main(const unsigned short* __restrict__ adj_bf, const unsigned short* __restrict__ sup_t,
            float* __restrict__ part) {
    __shared__ unsigned short As[64 * 64];  // 8 KB bf16 A tile, swizzled
    __shared__ unsigned short Bs[256 * 64]; // 32 KB bf16 B tile, swizzled
    const int tid = threadIdx.x, lane = tid & 63, wid = tid >> 6;
    const int l15 = lane & 15, q4 = lane >> 4;
    const int m0 = blockIdx.x * 64;
    const int kbase = blockIdx.y * KSTRIP;

    // A staging: 2 rounds x (256 thr x 16B) = 8 KB; rows of 64 bf16 = 8 chunks of 16B
    uint32_t aoff[2], alds[2];
#pragma unroll
    for (int r = 0; r < 2; ++r) {
        int idx = r * 256 + tid;
        int row = idx >> 3;
        int cg = (idx & 7) ^ (row & 7);
        aoff[r] = (uint32_t)(m0 + row) * N_ROWS + kbase + cg * 8;
        alds[r] = (uint32_t)(r * 2048 + wid * 512);  // ushort offset, wave-uniform
    }
    // B staging: 8 rounds x 4 KB = 32 KB
    uint32_t boff[8], blds[8];
#pragma unroll
    for (int r = 0; r < 8; ++r) {
        int idx = r * 256 + tid;
        int row = idx >> 3;
        int cg = (idx & 7) ^ (row & 7);
        boff[r] = (uint32_t)row * N_ROWS + kbase + cg * 8;
        blds[r] = (uint32_t)(r * 2048 + wid * 512);
    }

    const int ra7 = l15 & 7;
    const s16x8* aptr[4][2];
    const s16x8* bptr[4][2];
#pragma unroll
    for (int a = 0; a < 4; ++a)
#pragma unroll
        for (int h = 0; h < 2; ++h)
            aptr[a][h] = (const s16x8*)(As + (a * 16 + l15) * 64 + (((h * 4 + q4) ^ ra7) * 8));
#pragma unroll
    for (int b = 0; b < 4; ++b)
#pragma unroll
        for (int h = 0; h < 2; ++h)
            bptr[b][h] = (const s16x8*)(Bs + (wid * 64 + b * 16 + l15) * 64
                                        + (((h * 4 + q4) ^ ra7) * 8));

    f32x4 acc[4][4];
#pragma unroll
    for (int a = 0; a < 4; ++a)
#pragma unroll
        for (int b = 0; b < 4; ++b) acc[a][b] = (f32x4){0.f, 0.f, 0.f, 0.f};

#pragma unroll 1
    for (int it = 0; it < KSTRIP / BK; ++it) {
        __syncthreads();
#pragma unroll
        for (int r = 0; r < 2; ++r) gl_lds16(adj_bf + aoff[r], As + alds[r]);
#pragma unroll
        for (int r = 0; r < 8; ++r) gl_lds16(sup_t + boff[r], Bs + blds[r]);
        __syncthreads();
#pragma unroll
        for (int h = 0; h < 2; ++h) {
            s16x8 af[4];
#pragma unroll
            for (int a = 0; a < 4; ++a) af[a] = *aptr[a][h];
#pragma unroll
            for (int b = 0; b < 4; ++b) {
                s16x8 bf = *bptr[b][h];
#pragma unroll
                for (int a = 0; a < 4; ++a)
                    acc[a][b] = __builtin_amdgcn_mfma_f32_16x16x32_bf16(af[a], bf, acc[a][b], 0, 0, 0);
            }
        }
#pragma unroll
        for (int r = 0; r < 2; ++r) aoff[r] += BK;
#pragma unroll
        for (int r = 0; r < 8; ++r) boff[r] += BK;
    }

    float* p = part + (size_t)blockIdx.y * ((size_t)N_ROWS * F_DIM);
#pragma unroll
    for (int a = 0; a < 4; ++a) {
        const int rbase = m0 + a * 16 + q4 * 4;
#pragma unroll
        for (int b = 0; b < 4; ++b) {
            const int col = wid * 64 + b * 16 + l15;
            f32x4 c = acc[a][b];
#pragma unroll
            for (int r = 0; r < 4; ++r)
                p[(size_t)(rbase + r) * F_DIM + col] = c[r];
        }
    }
}

// ---------------- K4: out = d_i * (sum_s part_s + sup') + bias ----------------
__global__ void k_reduce(const float* __restrict__ part, const unsigned short* __restrict__ sup,
                         const float* __restrict__ dvec, const float* __restrict__ bias,
                         float* __restrict__ out) {
    const int gid = blockIdx.x * 256 + threadIdx.x;
    const int row = gid >> 6;
    const int c = (gid & 63) * 4;
    const size_t off = (size_t)row * F_DIM + c;
    const size_t PS = (size_t)N_ROWS * F_DIM;
    f32x4 v = *(const f32x4*)(part + off);
#pragma unroll
    for (int s = 1; s < SPLITK; ++s) v += *(const f32x4*)(part + s * PS + off);
    const float d = dvec[row];
    const unsigned short* sp = sup + off;
    const f32x4 bb = *(const f32x4*)(bias + c);
    f32x4 o;
#pragma unroll
    for (int r = 0; r < 4; ++r) o[r] = d * (v[r] + bf2f(sp[r])) + bb[r];
    *(f32x4*)(out + off) = o;
}

extern "C" void kernel_launch(void* const* d_in, const int* in_sizes, int n_in,
                              void* d_out, int out_size, void* d_ws, size_t ws_size,
                              hipStream_t stream) {
    const float* input  = (const float*)d_in[0];
    const float* adj    = (const float*)d_in[1];
    const float* weight = (const float*)d_in[2];
    const float* bias   = (const float*)d_in[3];
    float* out = (float*)d_out;

    char* ws = (char*)d_ws;
    unsigned short* adj_bf = (unsigned short*)ws;                                   // 128 MB
    char* ws2 = ws + (size_t)N_ROWS * N_ROWS * 2;
    float* dvec           = (float*)ws2;                                            // 32 KB
    unsigned short* wt    = (unsigned short*)(ws2 + (32 << 10));                    // 128 KB
    unsigned short* sup   = (unsigned short*)(ws2 + (32 << 10) + (128 << 10));      // 4 MB
    unsigned short* sup_t = (unsigned short*)(ws2 + (32 << 10) + (128 << 10)
                                              + (size_t)N_ROWS * F_DIM * 2);        // 4 MB
    float* part           = (float*)(ws2 + (32 << 10) + (128 << 10)
                                     + 2 * (size_t)N_ROWS * F_DIM * 2);             // 32 MB

    k_wt<<<dim3(F_DIM), dim3(F_DIM), 0, stream>>>(weight, wt);
    k_rowsum<<<dim3(N_ROWS), dim3(256), 0, stream>>>(adj, dvec, adj_bf);
    k_support<<<dim3(128, 2), dim3(256), 0, stream>>>(input, wt, dvec, sup, sup_t);
    k_main<<<dim3(128, SPLITK), dim3(256), 0, stream>>>(adj_bf, sup_t, part);
    k_reduce<<<dim3((N_ROWS * F_DIM / 4) / 256), dim3(256), 0, stream>>>(part, sup, dvec, bias, out);
}